// Round 4
// baseline (53.666 us; speedup 1.0000x reference)
//
#include <hip/hip_runtime.h>
#include <math.h>

#define NB 4096
#define ND 128
#define NCS 8         // column splits
#define BI 32         // rows per block
#define BJ 512        // cols per block (4 waves x 128)
#define NBI (NB / BI) // 128 row stripes

typedef __bf16 bf16x8 __attribute__((ext_vector_type(8)));
typedef __bf16 bf16x4 __attribute__((ext_vector_type(4)));
typedef float  f32x4  __attribute__((ext_vector_type(4)));

// ws layout:
//   [0, 1 MB)                  fnb   bf16[NB][ND]
//   [1 MB, 1 MB + 384 KB)      partials f32[NCS][NB][3]
//   [CTRL_OFF ...)             int cnt[NBI]; int gcnt; float acc;
#define FNB_BYTES   ((size_t)NB * ND * 2)          // 1048576
#define PART_BYTES  ((size_t)NCS * NB * 3 * 4)     // 393216
#define CTRL_OFF    (FNB_BYTES + PART_BYTES)       // 1441792 (512-aligned)

// ---- pass 1: L2-normalize rows -> bf16; also re-zero control words ----------
__global__ __launch_bounds__(256) void rownorm_kernel(
    const float* __restrict__ f, __bf16* __restrict__ fnb, int* __restrict__ ctrl)
{
    if (blockIdx.x == 0 && threadIdx.x < NBI + 2)   // cnt[128], gcnt, acc
        ctrl[threadIdx.x] = 0;
    const int t   = blockIdx.x * 256 + threadIdx.x;
    const int row = t >> 5;
    const int c   = (t & 31) << 2;
    float4 v = *reinterpret_cast<const float4*>(f + (size_t)row * ND + c);
    float ss = v.x * v.x + v.y * v.y + v.z * v.z + v.w * v.w;
#pragma unroll
    for (int off = 1; off < 32; off <<= 1) ss += __shfl_xor(ss, off, 64);
    const float inv = 1.0f / fmaxf(sqrtf(ss), 1e-12f);
    bf16x4 o;
    o[0] = (__bf16)(v.x * inv); o[1] = (__bf16)(v.y * inv);
    o[2] = (__bf16)(v.z * inv); o[3] = (__bf16)(v.w * inv);
    *reinterpret_cast<bf16x4*>(fnb + (size_t)row * ND + c) = o;
}

// ---- pass 2: sim-GEMM via MFMA + fused stats + fused final reduction --------
// grid: blockIdx.x = bi*NCS + cs ; 256 thr = 4 waves; block tile 32 x 512
__global__ __launch_bounds__(256) void supcon_mfma(
    const __bf16* __restrict__ fn, const int* __restrict__ labels,
    float* __restrict__ partials, int* __restrict__ cnt, int* __restrict__ gcnt,
    float* __restrict__ acc_ws, float* __restrict__ out)
{
    __shared__ float redL[4][BI][3];
    __shared__ int sdone;
    const int t    = threadIdx.x;
    const int wc   = t >> 6, lane = t & 63;
    const int bi   = blockIdx.x >> 3;          // 0..127
    const int cs   = blockIdx.x & (NCS - 1);   // 0..7
    const int ib   = bi * BI;
    const int jb   = cs * BJ + wc * 128;
    const int lr   = lane & 15;                // row/col residue in 16-tile
    const int lk   = lane >> 4;                // k-group 0..3

    // preload A fragments (16B contiguous per lane, row-major)
    bf16x8 a[2][4];
#pragma unroll
    for (int it = 0; it < 2; ++it)
#pragma unroll
        for (int ks = 0; ks < 4; ++ks)
            a[it][ks] = *reinterpret_cast<const bf16x8*>(
                fn + (size_t)(ib + it * 16 + lr) * ND + ks * 32 + lk * 8);

    int labi[2][4];
#pragma unroll
    for (int it = 0; it < 2; ++it)
#pragma unroll
        for (int r = 0; r < 4; ++r)
            labi[it][r] = labels[ib + it * 16 + lk * 4 + r];

    int labj8[8];
#pragma unroll
    for (int jt = 0; jt < 8; ++jt) labj8[jt] = labels[jb + jt * 16 + lr];

    float es[2][4] = {}, ps[2][4] = {}, np[2][4] = {};

#pragma unroll
    for (int jt = 0; jt < 8; ++jt) {
        bf16x8 b[4];
#pragma unroll
        for (int ks = 0; ks < 4; ++ks)
            b[ks] = *reinterpret_cast<const bf16x8*>(
                fn + (size_t)(jb + jt * 16 + lr) * ND + ks * 32 + lk * 8);
        f32x4 acc[2] = {};
#pragma unroll
        for (int ks = 0; ks < 4; ++ks) {
            acc[0] = __builtin_amdgcn_mfma_f32_16x16x32_bf16(a[0][ks], b[ks], acc[0], 0, 0, 0);
            acc[1] = __builtin_amdgcn_mfma_f32_16x16x32_bf16(a[1][ks], b[ks], acc[1], 0, 0, 0);
        }
        // fused epilogue: C/D layout col = lane&15, row = (lane>>4)*4 + r
        const int jg   = jb + jt * 16 + lr;
        const int labj = labj8[jt];
#pragma unroll
        for (int it = 0; it < 2; ++it)
#pragma unroll
            for (int r = 0; r < 4; ++r) {
                const int   ig   = ib + it * 16 + lk * 4 + r;
                const float s    = acc[it][r];
                const float e    = __expf(s);
                const bool  self = (jg == ig);
                const bool  pos  = (labj == labi[it][r]) && !self;
                es[it][r] += self ? 0.f : e;
                ps[it][r] += pos ? s : 0.f;
                np[it][r] += pos ? 1.f : 0.f;
            }
    }

    // reduce across the 16 col-lanes
#pragma unroll
    for (int off = 1; off < 16; off <<= 1)
#pragma unroll
        for (int it = 0; it < 2; ++it)
#pragma unroll
            for (int r = 0; r < 4; ++r) {
                es[it][r] += __shfl_xor(es[it][r], off, 64);
                ps[it][r] += __shfl_xor(ps[it][r], off, 64);
                np[it][r] += __shfl_xor(np[it][r], off, 64);
            }
    if (lr == 0) {
#pragma unroll
        for (int it = 0; it < 2; ++it)
#pragma unroll
            for (int r = 0; r < 4; ++r) {
                const int rl = it * 16 + lk * 4 + r;
                redL[wc][rl][0] = es[it][r];
                redL[wc][rl][1] = ps[it][r];
                redL[wc][rl][2] = np[it][r];
            }
    }
    __syncthreads();
    // publish this block's 32-row partials at the coherence point (cross-XCD safe)
    if (t < BI) {
        float* p = partials + ((size_t)cs * NB + ib + t) * 3;
        atomicExch(&p[0], redL[0][t][0] + redL[1][t][0] + redL[2][t][0] + redL[3][t][0]);
        atomicExch(&p[1], redL[0][t][1] + redL[1][t][1] + redL[2][t][1] + redL[3][t][1]);
        atomicExch(&p[2], redL[0][t][2] + redL[1][t][2] + redL[2][t][2] + redL[3][t][2]);
    }
    __syncthreads();           // all publishes drained (waitcnt before barrier)
    if (t == 0) {
        __threadfence();
        sdone = atomicAdd(cnt + bi, 1);
    }
    __syncthreads();
    if (sdone == NCS - 1) {    // last block for this row stripe: finalize 32 rows
        float c = 0.f;
        if (t < BI) {
            float esf = 0.f, psf = 0.f, npf = 0.f;
#pragma unroll
            for (int cs2 = 0; cs2 < NCS; ++cs2) {
                float* p = partials + ((size_t)cs2 * NB + ib + t) * 3;
                esf += atomicAdd(&p[0], 0.0f);   // coherent reads
                psf += atomicAdd(&p[1], 0.0f);
                npf += atomicAdd(&p[2], 0.0f);
            }
            const float lse = logf(esf);
            c = -(psf - npf * lse) / ((npf + 1e-5f) * (float)NB);
        }
#pragma unroll
        for (int off = 1; off < 32; off <<= 1) c += __shfl_xor(c, off, 64);
        if (t == 0) {
            atomicAdd(acc_ws, c);
            __threadfence();
            const int g = atomicAdd(gcnt, 1);
            if (g == NBI - 1) {              // very last stripe finisher
                __threadfence();
                out[0] = atomicAdd(acc_ws, 0.0f);  // coherent read of full sum
            }
        }
    }
}

extern "C" void kernel_launch(void* const* d_in, const int* in_sizes, int n_in,
                              void* d_out, int out_size, void* d_ws, size_t ws_size,
                              hipStream_t stream) {
    const float* features = (const float*)d_in[0];
    const int*   labels   = (const int*)d_in[1];
    float* out = (float*)d_out;

    __bf16* fnb      = (__bf16*)d_ws;
    float*  partials = (float*)((char*)d_ws + FNB_BYTES);
    int*    ctrl     = (int*)((char*)d_ws + CTRL_OFF);
    int*    cnt      = ctrl;            // [NBI]
    int*    gcnt     = ctrl + NBI;      // [1]
    float*  acc_ws   = (float*)(ctrl + NBI + 1);

    rownorm_kernel<<<NB * 32 / 256, 256, 0, stream>>>(features, fnb, ctrl);
    supcon_mfma<<<NBI * NCS, 256, 0, stream>>>(fnb, labels, partials, cnt, gcnt, acc_ws, out);
}

// Round 5
// 36.560 us; speedup vs baseline: 1.4679x; 1.4679x over previous
//
#include <hip/hip_runtime.h>
#include <math.h>

#define NB 4096
#define ND 128
#define TT 128        // tile size (rows and cols); K = ND = 128 staged whole
#define NT (NB / TT)  // 32 tiles per dimension

typedef __bf16 bf16x8 __attribute__((ext_vector_type(8)));
typedef __bf16 bf16x4 __attribute__((ext_vector_type(4)));
typedef float  f32x4  __attribute__((ext_vector_type(4)));

// ---- pass 1: L2-normalize rows, emit bf16 ----------------------------------
__global__ __launch_bounds__(256) void rownorm_kernel(
    const float* __restrict__ f, __bf16* __restrict__ fnb)
{
    const int t   = blockIdx.x * 256 + threadIdx.x;
    const int row = t >> 5;
    const int c   = (t & 31) << 2;
    float4 v = *reinterpret_cast<const float4*>(f + (size_t)row * ND + c);
    float ss = v.x * v.x + v.y * v.y + v.z * v.z + v.w * v.w;
#pragma unroll
    for (int off = 1; off < 32; off <<= 1) ss += __shfl_xor(ss, off, 64);
    const float inv = 1.0f / fmaxf(sqrtf(ss), 1e-12f);
    bf16x4 o;
    o[0] = (__bf16)(v.x * inv); o[1] = (__bf16)(v.y * inv);
    o[2] = (__bf16)(v.z * inv); o[3] = (__bf16)(v.w * inv);
    *reinterpret_cast<bf16x4*>(fnb + (size_t)row * ND + c) = o;
}

// ---- pass 2: 128x128 LDS-staged sim-tile + MFMA + fused stats ---------------
// LDS fragment-major layout: global 16B chunk (row, c16) -> LDS chunk
//   (row>>4)*256 + (c16>>2)*64 + (c16&3)*16 + (row&15)
// so a wave's MFMA fragment read is base + lane*16 (contiguous, conflict-free).
__global__ __launch_bounds__(512, 4) void supcon_mfma(
    const __bf16* __restrict__ fn, const int* __restrict__ labels,
    float* __restrict__ partials)
{
    __shared__ __align__(16) __bf16 At[TT * ND];   // 32 KB
    __shared__ __align__(16) __bf16 Bt[TT * ND];   // 32 KB
    __shared__ float redL[2][TT][3];

    const int t    = threadIdx.x;
    const int lane = t & 63;
    const int wid  = t >> 6;
    const int wr   = wid >> 1;          // 0..3 : rows wr*32 .. +32
    const int wc   = wid & 1;           // 0..1 : cols wc*64 .. +64
    const int bi   = blockIdx.x >> 5;   // row tile 0..31
    const int cs   = blockIdx.x & 31;   // col tile 0..31
    const int lr   = lane & 15;
    const int lk   = lane >> 4;

    // ---- stage A (rows bi*128..) and B (rows cs*128..) tiles, fragment-major
    {
        const __bf16* gA = fn + (size_t)bi * TT * ND;
        const __bf16* gB = fn + (size_t)cs * TT * ND;
#pragma unroll
        for (int i = 0; i < 4; ++i) {
            const int id  = i * 512 + t;        // chunk 0..2047
            const int row = id >> 4;
            const int c16 = id & 15;
            const int dst = ((row >> 4) * 256 + (c16 >> 2) * 64 +
                             (c16 & 3) * 16 + (row & 15)) * 8;
            *reinterpret_cast<bf16x8*>(&At[dst]) =
                *reinterpret_cast<const bf16x8*>(gA + row * ND + c16 * 8);
            *reinterpret_cast<bf16x8*>(&Bt[dst]) =
                *reinterpret_cast<const bf16x8*>(gB + row * ND + c16 * 8);
        }
    }

    // labels (overlap with staging latency)
    int labi[2][4];
#pragma unroll
    for (int it = 0; it < 2; ++it)
#pragma unroll
        for (int r = 0; r < 4; ++r)
            labi[it][r] = labels[bi * TT + wr * 32 + it * 16 + lk * 4 + r];
    int labj[4];
#pragma unroll
    for (int jt = 0; jt < 4; ++jt)
        labj[jt] = labels[cs * TT + wc * 64 + jt * 16 + lr];

    __syncthreads();

    // A fragments: chunk base ((wr*2+it)*4+ks)*64 + lane  (contiguous 1KB/wave)
    bf16x8 a[2][4];
#pragma unroll
    for (int it = 0; it < 2; ++it)
#pragma unroll
        for (int ks = 0; ks < 4; ++ks)
            a[it][ks] = *reinterpret_cast<const bf16x8*>(
                &At[(((wr * 2 + it) * 4 + ks) * 64 + lane) * 8]);

    float es[2][4] = {}, ps[2][4] = {}, np[2][4] = {};

#pragma unroll
    for (int jt = 0; jt < 4; ++jt) {
        bf16x8 b[4];
#pragma unroll
        for (int ks = 0; ks < 4; ++ks)
            b[ks] = *reinterpret_cast<const bf16x8*>(
                &Bt[(((wc * 4 + jt) * 4 + ks) * 64 + lane) * 8]);
        f32x4 acc[2] = {};
#pragma unroll
        for (int ks = 0; ks < 4; ++ks) {
            acc[0] = __builtin_amdgcn_mfma_f32_16x16x32_bf16(a[0][ks], b[ks], acc[0], 0, 0, 0);
            acc[1] = __builtin_amdgcn_mfma_f32_16x16x32_bf16(a[1][ks], b[ks], acc[1], 0, 0, 0);
        }
        // epilogue: C/D layout col = lane&15, row = (lane>>4)*4 + r
        const int jg = cs * TT + wc * 64 + jt * 16 + lr;
        const int lj = labj[jt];
#pragma unroll
        for (int it = 0; it < 2; ++it)
#pragma unroll
            for (int r = 0; r < 4; ++r) {
                const int   ig   = bi * TT + wr * 32 + it * 16 + lk * 4 + r;
                const float s    = acc[it][r];
                const float e    = __expf(s);
                const bool  self = (jg == ig);
                const bool  pos  = (lj == labi[it][r]) && !self;
                es[it][r] += self ? 0.f : e;
                ps[it][r] += pos ? s : 0.f;
                np[it][r] += pos ? 1.f : 0.f;
            }
    }

    // reduce across the 16 col-lanes (offsets stay inside the 16-group)
#pragma unroll
    for (int off = 1; off < 16; off <<= 1)
#pragma unroll
        for (int it = 0; it < 2; ++it)
#pragma unroll
            for (int r = 0; r < 4; ++r) {
                es[it][r] += __shfl_xor(es[it][r], off, 64);
                ps[it][r] += __shfl_xor(ps[it][r], off, 64);
                np[it][r] += __shfl_xor(np[it][r], off, 64);
            }
    if (lr == 0) {
#pragma unroll
        for (int it = 0; it < 2; ++it)
#pragma unroll
            for (int r = 0; r < 4; ++r) {
                const int rl = wr * 32 + it * 16 + lk * 4 + r;
                redL[wc][rl][0] = es[it][r];
                redL[wc][rl][1] = ps[it][r];
                redL[wc][rl][2] = np[it][r];
            }
    }
    __syncthreads();
    if (t < TT) {   // fold the 2 col-halves; one deterministic writer per (cs,row)
        float* p = partials + ((size_t)cs * NB + bi * TT + t) * 3;
        p[0] = redL[0][t][0] + redL[1][t][0];
        p[1] = redL[0][t][1] + redL[1][t][1];
        p[2] = redL[0][t][2] + redL[1][t][2];
    }
}

// ---- pass 3: per-row loss + block-level reduce + atomic to out --------------
__global__ __launch_bounds__(256) void final_kernel(
    const float* __restrict__ partials, float* __restrict__ out)
{
    const int row = blockIdx.x * 256 + threadIdx.x;
    float es = 0.f, ps = 0.f, np = 0.f;
#pragma unroll
    for (int cs = 0; cs < NT; ++cs) {
        const float* p = partials + ((size_t)cs * NB + row) * 3;
        es += p[0]; ps += p[1]; np += p[2];
    }
    const float lse = logf(es);
    float c = -(ps - np * lse) / ((np + 1e-5f) * (float)NB);
#pragma unroll
    for (int off = 1; off < 64; off <<= 1) c += __shfl_xor(c, off, 64);
    __shared__ float sred[4];
    if ((threadIdx.x & 63) == 0) sred[threadIdx.x >> 6] = c;
    __syncthreads();
    if (threadIdx.x == 0) atomicAdd(out, sred[0] + sred[1] + sred[2] + sred[3]);
}

extern "C" void kernel_launch(void* const* d_in, const int* in_sizes, int n_in,
                              void* d_out, int out_size, void* d_ws, size_t ws_size,
                              hipStream_t stream) {
    const float* features = (const float*)d_in[0];
    const int*   labels   = (const int*)d_in[1];
    float* out = (float*)d_out;

    __bf16* fnb      = (__bf16*)d_ws;                                // 1 MB
    float*  partials = (float*)((char*)d_ws + (size_t)NB * ND * 2);  // 32*4096*3*4 = 1.5 MB

    hipMemsetAsync(d_out, 0, (size_t)out_size * sizeof(float), stream);
    rownorm_kernel<<<NB * 32 / 256, 256, 0, stream>>>(features, fnb);
    supcon_mfma<<<NT * NT, 512, 0, stream>>>(fnb, labels, partials);
    final_kernel<<<NB / 256, 256, 0, stream>>>(partials, out);
}

// Round 6
// 25.431 us; speedup vs baseline: 2.1103x; 1.4376x over previous
//
#include <hip/hip_runtime.h>
#include <math.h>

#define NB 4096
#define ND 128
#define TT 128        // tile size (rows and cols); K = ND = 128 staged whole
#define NT (NB / TT)  // 32 tiles per dimension

typedef __bf16 bf16x8 __attribute__((ext_vector_type(8)));
typedef __bf16 bf16x4 __attribute__((ext_vector_type(4)));
typedef float  f32x4  __attribute__((ext_vector_type(4)));

// ---- pass 1: L2-normalize rows, emit bf16 ----------------------------------
__global__ __launch_bounds__(256) void rownorm_kernel(
    const float* __restrict__ f, __bf16* __restrict__ fnb)
{
    const int t   = blockIdx.x * 256 + threadIdx.x;
    const int row = t >> 5;
    const int c   = (t & 31) << 2;
    float4 v = *reinterpret_cast<const float4*>(f + (size_t)row * ND + c);
    float ss = v.x * v.x + v.y * v.y + v.z * v.z + v.w * v.w;
#pragma unroll
    for (int off = 1; off < 32; off <<= 1) ss += __shfl_xor(ss, off, 64);
    const float inv = 1.0f / fmaxf(sqrtf(ss), 1e-12f);
    bf16x4 o;
    o[0] = (__bf16)(v.x * inv); o[1] = (__bf16)(v.y * inv);
    o[2] = (__bf16)(v.z * inv); o[3] = (__bf16)(v.w * inv);
    *reinterpret_cast<bf16x4*>(fnb + (size_t)row * ND + c) = o;
}

// ---- pass 2: 128x128 LDS-staged sim-tile + MFMA + fused stats ---------------
// LDS layout (16B chunks): (row, c16) -> slot row*16 + (c16 ^ (row&15)).
//   write: lanes vary c16 at fixed row  -> XOR sweeps all 16 bank-quads (free)
//   read : lanes vary row at fixed c16  -> XOR sweeps all 16 bank-quads (free)
// Operands SWAPPED vs naive: acc = mfma(j_frag, i_frag) so D col = i index
// (lane&15) -> row stats accumulate in-thread; cross-lane reduce = 2 steps.
__global__ __launch_bounds__(512, 4) void supcon_mfma(
    const __bf16* __restrict__ fn, const int* __restrict__ labels,
    float* __restrict__ partials)
{
    __shared__ __align__(16) __bf16 At[TT * ND];   // 32 KB (i rows)
    __shared__ __align__(16) __bf16 Bt[TT * ND];   // 32 KB (j rows)
    __shared__ float redL[2][TT][3];

    const int t    = threadIdx.x;
    const int lane = t & 63;
    const int wid  = t >> 6;
    const int wr   = wid >> 1;          // 0..3 : i rows wr*32 .. +32
    const int wc   = wid & 1;           // 0..1 : j cols wc*64 .. +64
    const int bi   = blockIdx.x >> 5;   // i tile 0..31
    const int cs   = blockIdx.x & 31;   // j tile 0..31
    const int lr   = lane & 15;
    const int lk   = lane >> 4;
    const int ib   = bi * TT;
    const int jb   = cs * TT;

    // ---- stage A (i rows) and B (j rows), XOR-swizzled, coalesced source ----
    {
        const __bf16* gA = fn + (size_t)ib * ND;
        const __bf16* gB = fn + (size_t)jb * ND;
#pragma unroll
        for (int i = 0; i < 4; ++i) {
            const int id  = i * 512 + t;          // chunk 0..2047
            const int row = id >> 4;
            const int c16 = id & 15;
            const int dst = (row * 16 + (c16 ^ (row & 15))) * 8;
            *reinterpret_cast<bf16x8*>(&At[dst]) =
                *reinterpret_cast<const bf16x8*>(gA + row * ND + c16 * 8);
            *reinterpret_cast<bf16x8*>(&Bt[dst]) =
                *reinterpret_cast<const bf16x8*>(gB + row * ND + c16 * 8);
        }
    }

    // labels / indices (overlap staging latency)
    int ig[2], labi[2];
#pragma unroll
    for (int it = 0; it < 2; ++it) {
        ig[it]   = ib + wr * 32 + it * 16 + lr;   // my i index (D col = lane&15)
        labi[it] = labels[ig[it]];
    }
    const int jg0 = jb + wc * 64 + lk * 4;        // D row = lk*4 + r
    int labj[4][4];
#pragma unroll
    for (int jt = 0; jt < 4; ++jt)
#pragma unroll
        for (int r = 0; r < 4; ++r)
            labj[jt][r] = labels[jg0 + jt * 16 + r];

    __syncthreads();

    // preload i-side fragments (MFMA B operand): row = wr*32+it*16+lr, c16 = ks*4+lk
    bf16x8 bfr[2][4];
#pragma unroll
    for (int it = 0; it < 2; ++it)
#pragma unroll
        for (int ks = 0; ks < 4; ++ks) {
            const int row = wr * 32 + it * 16 + lr;
            bfr[it][ks] = *reinterpret_cast<const bf16x8*>(
                &At[(row * 16 + ((ks * 4 + lk) ^ lr)) * 8]);
        }

    float es[2] = {0.f, 0.f}, ps[2] = {0.f, 0.f}, np[2] = {0.f, 0.f};

#pragma unroll
    for (int jt = 0; jt < 4; ++jt) {
        // j-side fragments (MFMA A operand)
        bf16x8 af[4];
#pragma unroll
        for (int ks = 0; ks < 4; ++ks) {
            const int row = wc * 64 + jt * 16 + lr;
            af[ks] = *reinterpret_cast<const bf16x8*>(
                &Bt[(row * 16 + ((ks * 4 + lk) ^ lr)) * 8]);
        }
        f32x4 acc[2] = {};
#pragma unroll
        for (int ks = 0; ks < 4; ++ks) {
            acc[0] = __builtin_amdgcn_mfma_f32_16x16x32_bf16(af[ks], bfr[0][ks], acc[0], 0, 0, 0);
            acc[1] = __builtin_amdgcn_mfma_f32_16x16x32_bf16(af[ks], bfr[1][ks], acc[1], 0, 0, 0);
        }
        // epilogue: D[row = j' = lk*4+r][col = i' = lr]; stats accumulate in-thread
#pragma unroll
        for (int it = 0; it < 2; ++it)
#pragma unroll
            for (int r = 0; r < 4; ++r) {
                const int   jgv  = jg0 + jt * 16 + r;
                const float s    = acc[it][r];
                const float e    = __expf(s);
                const bool  self = (jgv == ig[it]);
                const bool  pos  = (labj[jt][r] == labi[it]) && !self;
                es[it] += self ? 0.f : e;
                ps[it] += pos ? s : 0.f;
                np[it] += pos ? 1.f : 0.f;
            }
    }

    // cross-lane reduce over the 4 lk-groups only (offsets 16, 32)
#pragma unroll
    for (int off = 16; off < 64; off <<= 1)
#pragma unroll
        for (int it = 0; it < 2; ++it) {
            es[it] += __shfl_xor(es[it], off, 64);
            ps[it] += __shfl_xor(ps[it], off, 64);
            np[it] += __shfl_xor(np[it], off, 64);
        }
    if (lk == 0) {
#pragma unroll
        for (int it = 0; it < 2; ++it) {
            const int rl = wr * 32 + it * 16 + lr;
            redL[wc][rl][0] = es[it];
            redL[wc][rl][1] = ps[it];
            redL[wc][rl][2] = np[it];
        }
    }
    __syncthreads();
    if (t < TT) {   // fold the 2 col-halves; one deterministic writer per (cs,row)
        float* p = partials + ((size_t)cs * NB + ib + t) * 3;
        p[0] = redL[0][t][0] + redL[1][t][0];
        p[1] = redL[0][t][1] + redL[1][t][1];
        p[2] = redL[0][t][2] + redL[1][t][2];
    }
}

// ---- pass 3: per-row loss + block-level reduce + atomic to out --------------
__global__ __launch_bounds__(256) void final_kernel(
    const float* __restrict__ partials, float* __restrict__ out)
{
    const int row = blockIdx.x * 256 + threadIdx.x;
    float es = 0.f, ps = 0.f, np = 0.f;
#pragma unroll
    for (int cs = 0; cs < NT; ++cs) {
        const float* p = partials + ((size_t)cs * NB + row) * 3;
        es += p[0]; ps += p[1]; np += p[2];
    }
    const float lse = logf(es);
    float c = -(ps - np * lse) / ((np + 1e-5f) * (float)NB);
#pragma unroll
    for (int off = 1; off < 64; off <<= 1) c += __shfl_xor(c, off, 64);
    __shared__ float sred[4];
    if ((threadIdx.x & 63) == 0) sred[threadIdx.x >> 6] = c;
    __syncthreads();
    if (threadIdx.x == 0) atomicAdd(out, sred[0] + sred[1] + sred[2] + sred[3]);
}

extern "C" void kernel_launch(void* const* d_in, const int* in_sizes, int n_in,
                              void* d_out, int out_size, void* d_ws, size_t ws_size,
                              hipStream_t stream) {
    const float* features = (const float*)d_in[0];
    const int*   labels   = (const int*)d_in[1];
    float* out = (float*)d_out;

    __bf16* fnb      = (__bf16*)d_ws;                                // 1 MB
    float*  partials = (float*)((char*)d_ws + (size_t)NB * ND * 2);  // 1.5 MB

    hipMemsetAsync(d_out, 0, (size_t)out_size * sizeof(float), stream);
    rownorm_kernel<<<NB * 32 / 256, 256, 0, stream>>>(features, fnb);
    supcon_mfma<<<NT * NT, 512, 0, stream>>>(fnb, labels, partials);
    final_kernel<<<NB / 256, 256, 0, stream>>>(partials, out);
}

// Round 7
// 21.786 us; speedup vs baseline: 2.4633x; 1.1673x over previous
//
#include <hip/hip_runtime.h>
#include <math.h>

#define NB 4096
#define ND 128
#define TT 256        // tile size (rows and cols); K = ND = 128 staged whole
#define NT (NB / TT)  // 16 tiles per dimension; grid = 256 = 1 block/CU

typedef __bf16 bf16x8 __attribute__((ext_vector_type(8)));
typedef __bf16 bf16x4 __attribute__((ext_vector_type(4)));
typedef float  f32x4  __attribute__((ext_vector_type(4)));

// ---- pass 1: L2-normalize rows -> bf16; lane0 of block0 zeroes out[0] -------
__global__ __launch_bounds__(256) void rownorm_kernel(
    const float* __restrict__ f, __bf16* __restrict__ fnb, float* __restrict__ out)
{
    if (blockIdx.x == 0 && threadIdx.x == 0) out[0] = 0.f;
    const int t   = blockIdx.x * 256 + threadIdx.x;
    const int row = t >> 5;
    const int c   = (t & 31) << 2;
    float4 v = *reinterpret_cast<const float4*>(f + (size_t)row * ND + c);
    float ss = v.x * v.x + v.y * v.y + v.z * v.z + v.w * v.w;
#pragma unroll
    for (int off = 1; off < 32; off <<= 1) ss += __shfl_xor(ss, off, 64);
    const float inv = 1.0f / fmaxf(sqrtf(ss), 1e-12f);
    bf16x4 o;
    o[0] = (__bf16)(v.x * inv); o[1] = (__bf16)(v.y * inv);
    o[2] = (__bf16)(v.z * inv); o[3] = (__bf16)(v.w * inv);
    *reinterpret_cast<bf16x4*>(fnb + (size_t)row * ND + c) = o;
}

// ---- pass 2: 256x256 LDS-staged sim-tile + MFMA + fused stats ---------------
// LDS layout (16B chunks): (row, c16) -> slot row*16 + (c16 ^ (row&15)).
// Swapped operands: acc = mfma(j_frag, i_frag) so D col (lane&15) = i index;
// stats accumulate in-thread, cross-lane reduce = offsets 16/32 only.
// 8 waves: wr = wid>>1 (4 x 64 i-rows), wc = wid&1 (2 x 128 j-cols).
__global__ __launch_bounds__(512, 2) void supcon_mfma(
    const __bf16* __restrict__ fn, const int* __restrict__ labels,
    float* __restrict__ partials)
{
    __shared__ __align__(16) __bf16 At[TT * ND];   // 64 KB (i rows)
    __shared__ __align__(16) __bf16 Bt[TT * ND];   // 64 KB (j rows)
    __shared__ float redL[2][TT][3];               // 6 KB

    const int t    = threadIdx.x;
    const int lane = t & 63;
    const int wid  = t >> 6;
    const int wr   = wid >> 1;          // 0..3 : i rows wr*64 .. +64
    const int wc   = wid & 1;           // 0..1 : j cols wc*128 .. +128
    const int bi   = blockIdx.x >> 4;   // i tile 0..15
    const int cs   = blockIdx.x & 15;   // j tile 0..15
    const int lr   = lane & 15;
    const int lk   = lane >> 4;
    const int ib   = bi * TT;
    const int jb   = cs * TT;

    // ---- stage A (i rows) and B (j rows), XOR-swizzled, coalesced source ----
    {
        const __bf16* gA = fn + (size_t)ib * ND;
        const __bf16* gB = fn + (size_t)jb * ND;
#pragma unroll
        for (int i = 0; i < 8; ++i) {
            const int id  = i * 512 + t;          // chunk 0..4095
            const int row = id >> 4;
            const int c16 = id & 15;
            const int dst = (row * 16 + (c16 ^ (row & 15))) * 8;
            *reinterpret_cast<bf16x8*>(&At[dst]) =
                *reinterpret_cast<const bf16x8*>(gA + row * ND + c16 * 8);
            *reinterpret_cast<bf16x8*>(&Bt[dst]) =
                *reinterpret_cast<const bf16x8*>(gB + row * ND + c16 * 8);
        }
    }

    // my i indices / labels (overlap staging latency)
    int ig[4], labi[4];
#pragma unroll
    for (int it = 0; it < 4; ++it) {
        ig[it]   = ib + wr * 64 + it * 16 + lr;   // D col = lane&15
        labi[it] = labels[ig[it]];
    }

    __syncthreads();

    // preload i-side fragments (MFMA B operand)
    bf16x8 bfr[4][4];
#pragma unroll
    for (int it = 0; it < 4; ++it)
#pragma unroll
        for (int ks = 0; ks < 4; ++ks) {
            const int row = wr * 64 + it * 16 + lr;
            bfr[it][ks] = *reinterpret_cast<const bf16x8*>(
                &At[(row * 16 + ((ks * 4 + lk) ^ lr)) * 8]);
        }

    float es[4] = {}, ps[4] = {}, np[4] = {};

#pragma unroll
    for (int jt = 0; jt < 8; ++jt) {
        // j-side fragments (MFMA A operand)
        bf16x8 af[4];
#pragma unroll
        for (int ks = 0; ks < 4; ++ks) {
            const int row = wc * 128 + jt * 16 + lr;
            af[ks] = *reinterpret_cast<const bf16x8*>(
                &Bt[(row * 16 + ((ks * 4 + lk) ^ lr)) * 8]);
        }
        f32x4 acc[4] = {};
#pragma unroll
        for (int ks = 0; ks < 4; ++ks)
#pragma unroll
            for (int it = 0; it < 4; ++it)
                acc[it] = __builtin_amdgcn_mfma_f32_16x16x32_bf16(af[ks], bfr[it][ks], acc[it], 0, 0, 0);

        // j labels for this 16-tile: contiguous int4 per lk group
        const int jg0 = jb + wc * 128 + jt * 16 + lk * 4;   // D row = lk*4 + r
        const int4 lj4 = *reinterpret_cast<const int4*>(&labels[jg0]);
        const int lj[4] = {lj4.x, lj4.y, lj4.z, lj4.w};

        // epilogue: D[row = j-local = lk*4+r][col = i-local = lr]
#pragma unroll
        for (int it = 0; it < 4; ++it)
#pragma unroll
            for (int r = 0; r < 4; ++r) {
                const int   jgv  = jg0 + r;
                const float s    = acc[it][r];
                const float e    = __expf(s);
                const bool  self = (jgv == ig[it]);
                const bool  pos  = (lj[r] == labi[it]) && !self;
                es[it] += self ? 0.f : e;
                ps[it] += pos ? s : 0.f;
                np[it] += pos ? 1.f : 0.f;
            }
    }

    // cross-lane reduce over the 4 lk-groups only (offsets 16, 32)
#pragma unroll
    for (int off = 16; off < 64; off <<= 1)
#pragma unroll
        for (int it = 0; it < 4; ++it) {
            es[it] += __shfl_xor(es[it], off, 64);
            ps[it] += __shfl_xor(ps[it], off, 64);
            np[it] += __shfl_xor(np[it], off, 64);
        }
    if (lk == 0) {
#pragma unroll
        for (int it = 0; it < 4; ++it) {
            const int rl = wr * 64 + it * 16 + lr;
            redL[wc][rl][0] = es[it];
            redL[wc][rl][1] = ps[it];
            redL[wc][rl][2] = np[it];
        }
    }
    __syncthreads();
    if (t < TT) {   // fold the 2 col-halves; one deterministic writer per (cs,row)
        float* p = partials + ((size_t)cs * NB + ib + t) * 3;
        p[0] = redL[0][t][0] + redL[1][t][0];
        p[1] = redL[0][t][1] + redL[1][t][1];
        p[2] = redL[0][t][2] + redL[1][t][2];
    }
}

// ---- pass 3: per-row loss + block-level reduce + atomic to out --------------
__global__ __launch_bounds__(256) void final_kernel(
    const float* __restrict__ partials, float* __restrict__ out)
{
    const int row = blockIdx.x * 256 + threadIdx.x;
    float es = 0.f, ps = 0.f, np = 0.f;
#pragma unroll
    for (int cs = 0; cs < NT; ++cs) {
        const float* p = partials + ((size_t)cs * NB + row) * 3;
        es += p[0]; ps += p[1]; np += p[2];
    }
    const float lse = logf(es);
    float c = -(ps - np * lse) / ((np + 1e-5f) * (float)NB);
#pragma unroll
    for (int off = 1; off < 64; off <<= 1) c += __shfl_xor(c, off, 64);
    __shared__ float sred[4];
    if ((threadIdx.x & 63) == 0) sred[threadIdx.x >> 6] = c;
    __syncthreads();
    if (threadIdx.x == 0) atomicAdd(out, sred[0] + sred[1] + sred[2] + sred[3]);
}

extern "C" void kernel_launch(void* const* d_in, const int* in_sizes, int n_in,
                              void* d_out, int out_size, void* d_ws, size_t ws_size,
                              hipStream_t stream) {
    const float* features = (const float*)d_in[0];
    const int*   labels   = (const int*)d_in[1];
    float* out = (float*)d_out;

    __bf16* fnb      = (__bf16*)d_ws;                                // 1 MB
    float*  partials = (float*)((char*)d_ws + (size_t)NB * ND * 2);  // 16*4096*3*4 = 768 KB

    rownorm_kernel<<<NB * 32 / 256, 256, 0, stream>>>(features, fnb, out);
    supcon_mfma<<<NT * NT, 512, 0, stream>>>(fnb, labels, partials);
    final_kernel<<<NB / 256, 256, 0, stream>>>(partials, out);
}